// Round 7
// baseline (165.372 us; speedup 1.0000x reference)
//
#include <hip/hip_runtime.h>
#include <hip/hip_fp16.h>

#define H0 200
#define W0 304
#define H1 100
#define W1 152
#define H2 50
#define W2 76
#define CPL 256   // channels per level
#define CTOT 768
#define OH 7
#define OW 7
#define NPOS 49
#define CBLK 128   // channels per stage-2 block
#define SROWP 131  // sout row stride (floats)
#define UXMAX 40   // max x-strips for separable row (geometry bound: <=37)

#define P0 (H0*W0)   // 60800
#define P1 (H1*W1)   // 15200
#define P2 (H2*W2)   // 3800
#define T0_OFF ((size_t)0)
#define T1_OFF ((size_t)P0*CPL)
#define T2_OFF ((size_t)P0*CPL + (size_t)P1*CPL)
#define WS_ELEMS ((size_t)P0*CPL + (size_t)P1*CPL + (size_t)P2*CPL)
#define WS_BYTES (WS_ELEMS * 2)   // fp16 workspace: 40,857,600 B

__device__ __forceinline__ float hat01(float d) {
    return fmaxf(0.0f, 1.0f - fabsf(d));
}

__device__ __forceinline__ unsigned short f2h_rne(float x) {
    return __half_as_ushort(__float2half_rn(x));
}

// ------------- Stage 1: fused [C][P] fp32 -> [P][C] fp16 transpose ----------
__global__ void __launch_bounds__(256)
transpose_all_kernel(const float* __restrict__ f0, const float* __restrict__ f1,
                     const float* __restrict__ f2,
                     unsigned short* __restrict__ T0,
                     unsigned short* __restrict__ T1,
                     unsigned short* __restrict__ T2, int n0, int n01) {
    __shared__ unsigned short tile[64][72];   // [p_local][c_local]
    int b = blockIdx.x;
    const float* in; unsigned short* outp; int P; int rel;
    if (b < n0)       { in = f0; outp = T0; P = P0; rel = b; }
    else if (b < n01) { in = f1; outp = T1; P = P1; rel = b - n0; }
    else              { in = f2; outp = T2; P = P2; rel = b - n01; }
    int p0 = (rel >> 2) * 64;
    int c0 = (rel & 3) * 64;

    int q = threadIdx.x & 15;     // p-quad
    int r = threadIdx.x >> 4;     // 0..15 (c)
    bool full = (p0 + 64 <= P);
#pragma unroll
    for (int i = 0; i < 4; ++i) {
        int c = c0 + r + 16 * i;
        int p = p0 + 4 * q;
        float4 v;
        if (full) {
            v = *(const float4*)(in + (size_t)c * P + p);
        } else {
            v.x = (p + 0 < P) ? in[(size_t)c * P + p + 0] : 0.0f;
            v.y = (p + 1 < P) ? in[(size_t)c * P + p + 1] : 0.0f;
            v.z = (p + 2 < P) ? in[(size_t)c * P + p + 2] : 0.0f;
            v.w = (p + 3 < P) ? in[(size_t)c * P + p + 3] : 0.0f;
        }
        tile[4 * q + 0][r + 16 * i] = f2h_rne(v.x);
        tile[4 * q + 1][r + 16 * i] = f2h_rne(v.y);
        tile[4 * q + 2][r + 16 * i] = f2h_rne(v.z);
        tile[4 * q + 3][r + 16 * i] = f2h_rne(v.w);
    }
    __syncthreads();
    int q8 = threadIdx.x & 7;     // c-octet
    int r8 = threadIdx.x >> 3;    // 0..31 (p)
#pragma unroll
    for (int i = 0; i < 2; ++i) {
        int p = p0 + r8 + 32 * i;
        if (p < P) {
            uint4 w = *(const uint4*)&tile[r8 + 32 * i][8 * q8];
            *(uint4*)(outp + (size_t)p * CPL + c0 + 8 * q8) = w;
        }
    }
}

// ------------- Stage 2: channels-last RoIAlign, 128-ch slab per block -------
// R7: R0-R6 all plateaued at ~41us across occupancy 17-40%, ILP 2-18, C and
// inline-asm pipelines. The invariant is gather volume: 1.93M 256B segments
// (494MB) through L1 = ~48 B/cy/CU = the L1 port ceiling. Fix: request fewer
// bytes. RoIAlign is separable: out[oh][ow] = SUM_x wx[ow][x] *
// (SUM_y wy[oh][y] * T[y][x]). For levels 1/2, per oh compute the
// y-collapsed row over the box's x-extent (ux<=37 strips) ONCE into LDS
// (fp32), then all 7 ow positions read LDS. Segments: 7*TT*ux vs 49*TT*TT
// (~2x fewer). L0 (4x4 taps, sparse support) keeps the direct path.
__device__ __forceinline__ void tap_loop_l0(const unsigned short* __restrict__ T,
                                            const int (*__restrict__ s_idx)[6],
                                            const float (*__restrict__ s_w)[6],
                                            float (*__restrict__ sout)[SROWP],
                                            int pstart, int pcount, int col,
                                            unsigned laneByte) {
    const char* Tb = (const char*)T;
    const __half2 hz = __float2half2_rn(0.0f);
    for (int pi = 0; pi < pcount; ++pi) {
        const int pos = pstart + pi;
        const int oh = pos / 7;
        const int ow = pos - oh * 7;
        unsigned yb[4]; float yw[4];
#pragma unroll
        for (int j2 = 0; j2 < 4; ++j2) {
            yb[j2] = (unsigned)s_idx[oh][j2] + laneByte;
            yw[j2] = s_w[oh][j2];
        }
        unsigned xb[4]; __half2 xw2[4];
#pragma unroll
        for (int j2 = 0; j2 < 4; ++j2) {
            xb[j2] = (unsigned)s_idx[7 + ow][j2];
            xw2[j2] = __float2half2_rn(s_w[7 + ow][j2]);
        }
        float a0 = 0.f, a1 = 0.f, a2 = 0.f, a3 = 0.f;
        float a4 = 0.f, a5 = 0.f, a6 = 0.f, a7 = 0.f;
#pragma unroll
        for (int r = 0; r < 4; ++r) {
            __half2 q0 = hz, q1 = hz, q2 = hz, q3 = hz;
#pragma unroll
            for (int b = 0; b < 4; ++b) {
                uint4 v = *(const uint4*)(Tb + (yb[r] + xb[b]));
                const __half2 xw = xw2[b];
                q0 = __hfma2(xw, *(const __half2*)&v.x, q0);
                q1 = __hfma2(xw, *(const __half2*)&v.y, q1);
                q2 = __hfma2(xw, *(const __half2*)&v.z, q2);
                q3 = __hfma2(xw, *(const __half2*)&v.w, q3);
            }
            const float wa = yw[r];
            a0 = fmaf(wa, __low2float(q0), a0);  a1 = fmaf(wa, __high2float(q0), a1);
            a2 = fmaf(wa, __low2float(q1), a2);  a3 = fmaf(wa, __high2float(q1), a3);
            a4 = fmaf(wa, __low2float(q2), a4);  a5 = fmaf(wa, __high2float(q2), a5);
            a6 = fmaf(wa, __low2float(q3), a6);  a7 = fmaf(wa, __high2float(q3), a7);
        }
        float4 o0, o1;
        o0.x = a0 * 0.25f; o0.y = a1 * 0.25f; o0.z = a2 * 0.25f; o0.w = a3 * 0.25f;
        o1.x = a4 * 0.25f; o1.y = a5 * 0.25f; o1.z = a6 * 0.25f; o1.w = a7 * 0.25f;
        *(float4*)(&sout[pos][col])     = o0;
        *(float4*)(&sout[pos][col + 4]) = o1;
    }
}

// Separable path for levels 1/2. TT = taps per axis (6 for L1, 5 for L2).
// Phase A (per oh): 16 groups x 16 lanes build row[s][c] = SUM_t wy[oh][t] *
// T[y_t][xlo+s][c] in fp32 LDS (group g owns strips g, g+16, g+32; lane owns
// 8 ch). Phase B: threads 0..223 -> (ow = t>>5, 4 ch each) combine TT x-taps
// from LDS into sout. Barrier after each phase (14/block).
template<int TT>
__device__ __forceinline__ void sep_level(const unsigned short* __restrict__ T,
                                          const int (*__restrict__ s_idx)[6],
                                          const float (*__restrict__ s_w)[6],
                                          float (*__restrict__ sout)[SROWP],
                                          float* __restrict__ rowbuf,
                                          int tid, unsigned chalfByte) {
    // x-extent (byte offsets are idx*512 since x mul==1)
    int xloB = s_idx[7][0], xhiB = xloB;
#pragma unroll
    for (int o = 0; o < 7; ++o) {
#pragma unroll
        for (int t = 0; t < TT; ++t) {
            int v = s_idx[7 + o][t];
            xloB = min(xloB, v);
            xhiB = max(xhiB, v);
        }
    }
    const int ux = ((xhiB - xloB) >> 9) + 1;   // strips (<= 37 by geometry)
    const int g = tid >> 4;
    const int l16 = tid & 15;
    const char* Tbase = (const char*)T + chalfByte + (unsigned)(l16 * 16) + (unsigned)xloB;

    for (int oh = 0; oh < OH; ++oh) {
        // ---- Phase A: y-collapse into rowbuf ----
        for (int s = g; s < ux; s += 16) {
            const char* bp = Tbase + ((unsigned)s << 9);
            float a0 = 0.f, a1 = 0.f, a2 = 0.f, a3 = 0.f;
            float a4 = 0.f, a5 = 0.f, a6 = 0.f, a7 = 0.f;
#pragma unroll
            for (int t = 0; t < TT; ++t) {
                uint4 v = *(const uint4*)(bp + (unsigned)s_idx[oh][t]);
                const float wy = s_w[oh][t];
                float2 f0 = __half22float2(*(const __half2*)&v.x);
                float2 f1 = __half22float2(*(const __half2*)&v.y);
                float2 f2 = __half22float2(*(const __half2*)&v.z);
                float2 f3 = __half22float2(*(const __half2*)&v.w);
                a0 = fmaf(wy, f0.x, a0); a1 = fmaf(wy, f0.y, a1);
                a2 = fmaf(wy, f1.x, a2); a3 = fmaf(wy, f1.y, a3);
                a4 = fmaf(wy, f2.x, a4); a5 = fmaf(wy, f2.y, a5);
                a6 = fmaf(wy, f3.x, a6); a7 = fmaf(wy, f3.y, a7);
            }
            float4* rp = (float4*)&rowbuf[s * CBLK + l16 * 8];
            rp[0] = make_float4(a0, a1, a2, a3);
            rp[1] = make_float4(a4, a5, a6, a7);
        }
        __syncthreads();
        // ---- Phase B: x-combine from rowbuf ----
        if (tid < 224) {
            const int ow = tid >> 5;
            const int ch = (tid & 31) * 4;
            float b0 = 0.f, b1 = 0.f, b2 = 0.f, b3 = 0.f;
#pragma unroll
            for (int t = 0; t < TT; ++t) {
                int s = (s_idx[7 + ow][t] - xloB) >> 9;
                s = min(s, UXMAX - 1);                 // safety (never triggers)
                const float wx = s_w[7 + ow][t];
                const float4 rv = *(const float4*)&rowbuf[s * CBLK + ch];
                b0 = fmaf(wx, rv.x, b0); b1 = fmaf(wx, rv.y, b1);
                b2 = fmaf(wx, rv.z, b2); b3 = fmaf(wx, rv.w, b3);
            }
            const int pos = oh * 7 + ow;
            *(float4*)(&sout[pos][ch]) =
                make_float4(b0 * 0.25f, b1 * 0.25f, b2 * 0.25f, b3 * 0.25f);
        }
        __syncthreads();
    }
}

__global__ void __launch_bounds__(256, 3)
roi_align_sep_kernel(const unsigned short* __restrict__ T0p,
                     const unsigned short* __restrict__ T1p,
                     const unsigned short* __restrict__ T2p,
                     const float* __restrict__ boxes,
                     const int* __restrict__ img_h_p,
                     const int* __restrict__ img_w_p,
                     float* __restrict__ out) {
    __shared__ float sout[NPOS][SROWP];          // [pos][c_local]
    __shared__ __align__(16) float rowbuf[UXMAX * CBLK];  // y-collapsed row (fp32)
    __shared__ int   s_idx[14][6];               // BYTE offsets: [0..6]=y(oh), [7..13]=x(ow)
    __shared__ float s_w[14][6];

    const int n = blockIdx.x;
    const int j = blockIdx.y;              // 0..5
    const int lev = j >> 1;
    const int chalf = j & 1;
    const int tid = threadIdx.x;

    const unsigned short* T; int Hc, Wc; float inv_s;
    if (lev == 0)      { T = T0p; Hc = H0; Wc = W0; inv_s = 1.0f;  }
    else if (lev == 1) { T = T1p; Hc = H1; Wc = W1; inv_s = 0.5f;  }
    else               { T = T2p; Hc = H2; Wc = W2; inv_s = 0.25f; }

    if (tid < 14) {
        int axis = (tid >= 7) ? 1 : 0;     // 0 = y, 1 = x
        int o = tid - axis * 7;
        float sx = (float)W0 / (float)img_w_p[0];
        float sy = (float)H0 / (float)img_h_p[0];
        float a1v, bs; int Hf, Hca, mul;
        if (axis) {
            a1v = boxes[n * 4 + 0] * sx;
            float a2v = boxes[n * 4 + 2] * sx;
            bs = fmaxf(a2v - a1v, 1.0f) * (1.0f / (float)OW);
            Hf = W0; Hca = Wc; mul = 1;
        } else {
            a1v = boxes[n * 4 + 1] * sy;
            float a2v = boxes[n * 4 + 3] * sy;
            bs = fmaxf(a2v - a1v, 1.0f) * (1.0f / (float)OH);
            Hf = H0; Hca = Hc; mul = Wc;
        }
        int idx[6]; float w[6];
#pragma unroll
        for (int t = 0; t < 6; ++t) { idx[t] = 0; w[t] = 0.0f; }
        if (lev == 0) {
#pragma unroll
            for (int r2 = 0; r2 < 2; ++r2) {
                float Y = a1v + ((float)o + 0.25f + 0.5f * (float)r2) * bs;
                float v = (Y >= -1.0f && Y <= (float)Hf) ? 1.0f : 0.0f;
                float Yc = fminf(fmaxf(Y, 0.0f), (float)(Hf - 1));
                int y0 = (int)Yc; float lf = Yc - (float)y0;
                idx[2 * r2]     = y0;                  w[2 * r2]     = (1.0f - lf) * v;
                idx[2 * r2 + 1] = min(y0 + 1, Hf - 1); w[2 * r2 + 1] = lf * v;
            }
        } else {
            int bases[2]; float w3[2][3];
#pragma unroll
            for (int r2 = 0; r2 < 2; ++r2) {
                float Y = a1v + ((float)o + 0.25f + 0.5f * (float)r2) * bs;
                float v = (Y >= -1.0f && Y <= (float)Hf) ? 1.0f : 0.0f;
                float Yc = fminf(fmaxf(Y, 0.0f), (float)(Hf - 1));
                int y0 = (int)Yc; float lf = Yc - (float)y0; float hf = 1.0f - lf;
                int yf1 = min(y0 + 1, Hf - 1);
                float yc0 = fminf(fmaxf(((float)y0 + 0.5f) * inv_s - 0.5f, 0.0f), (float)(Hca - 1));
                float yc1 = fminf(fmaxf(((float)yf1 + 0.5f) * inv_s - 0.5f, 0.0f), (float)(Hca - 1));
                int b2 = (int)yc0;
                bases[r2] = b2;
#pragma unroll
                for (int t2 = 0; t2 < 3; ++t2) {
                    float j2 = (float)(b2 + t2);
                    w3[r2][t2] = v * (hf * hat01(yc0 - j2) + lf * hat01(yc1 - j2));
                }
            }
            int dmax = (lev == 1) ? 3 : 2;   // geometry: box<=272px -> gap<=2.43/1.21
            int d = min(max(bases[1] - bases[0], 0), dmax);
            w[0] += w3[0][0]; w[1] += w3[0][1]; w[2] += w3[0][2];
            w[d] += w3[1][0]; w[d + 1] += w3[1][1]; w[d + 2] += w3[1][2];
#pragma unroll
            for (int t = 0; t < 6; ++t) idx[t] = min(bases[0] + t, Hca - 1);
        }
        // pre-scale to BYTE offset in T (row stride Wc*CPL elems, 2B/elem)
#pragma unroll
        for (int t = 0; t < 6; ++t) { s_idx[tid][t] = idx[t] * mul * CPL * 2; s_w[tid][t] = w[t]; }
    }
    __syncthreads();

    const unsigned chalfByte = (unsigned)(chalf * CBLK) * 2u;

    if (lev == 0) {
        const int grp = tid >> 4;              // 0..15: position group
        const int l16 = tid & 15;              // 0..15: 8 channels each
        const int col = l16 * 8;
        const unsigned laneByte = chalfByte + (unsigned)col * 2u;
        const int pstart = 3 * grp;
        const int pcount = (grp == 15) ? 4 : 3;
        tap_loop_l0(T, s_idx, s_w, sout, pstart, pcount, col, laneByte);
    } else if (lev == 1) {
        sep_level<6>(T, s_idx, s_w, sout, rowbuf, tid, chalfByte);
    } else {
        sep_level<5>(T, s_idx, s_w, sout, rowbuf, tid, chalfByte);
    }
    __syncthreads();

    // Writeback: out[n][lev*256 + chalf*128 + c][p], contiguous 128*49 floats.
    size_t obase = (size_t)n * CTOT * NPOS + (size_t)(lev * CPL + chalf * CBLK) * NPOS;
    int c = tid / NPOS;
    int p = tid - c * NPOS;
    for (int i = tid; i < CBLK * NPOS; i += 256) {
        out[obase + i] = sout[p][c];
        c += 5; p += 11;                   // 256 = 5*49 + 11
        if (p >= NPOS) { p -= NPOS; ++c; }
    }
}

// ---------------- Fallback (R1 kernel) if ws too small ----------------------
__device__ __forceinline__ void axis_w3_fb(int yf0, int Hf, int Hc, float inv_s,
                                           float lf, int& base, float* w) {
    int yf1 = min(yf0 + 1, Hf - 1);
    float hf = 1.0f - lf;
    float yc0 = fminf(fmaxf(((float)yf0 + 0.5f) * inv_s - 0.5f, 0.0f), (float)(Hc - 1));
    float yc1 = fminf(fmaxf(((float)yf1 + 0.5f) * inv_s - 0.5f, 0.0f), (float)(Hc - 1));
    base = (int)yc0;
#pragma unroll
    for (int r = 0; r < 3; ++r) {
        float j = (float)(base + r);
        w[r] = hf * hat01(yc0 - j) + lf * hat01(yc1 - j);
    }
}

__global__ void __launch_bounds__(256)
roi_align_fused_fb_kernel(const float* __restrict__ f0,
                          const float* __restrict__ f1,
                          const float* __restrict__ f2,
                          const float* __restrict__ boxes,
                          const int* __restrict__ img_h_p,
                          const int* __restrict__ img_w_p,
                          float* __restrict__ out,
                          int total) {
    int i = blockIdx.x * blockDim.x + threadIdx.x;
    if (i >= total) return;
    int ow = i % OW;
    int t = i / OW;
    int oh = t % OH; t /= OH;
    int c = t % CTOT;
    int n = t / CTOT;
    float sx = (float)W0 / (float)img_w_p[0];
    float sy = (float)H0 / (float)img_h_p[0];
    float bx1 = boxes[n * 4 + 0] * sx;
    float by1 = boxes[n * 4 + 1] * sy;
    float bw = fmaxf(boxes[n * 4 + 2] * sx - bx1, 1.0f) / OW;
    float bh = fmaxf(boxes[n * 4 + 3] * sy - by1, 1.0f) / OH;
    int level = c >> 8;
    int cl = c & (CPL - 1);
    const float* f;
    int Hc, Wc; float inv_s;
    if (level == 0)      { f = f0 + (size_t)cl * P0; Hc = H0; Wc = W0; inv_s = 1.0f;  }
    else if (level == 1) { f = f1 + (size_t)cl * P1; Hc = H1; Wc = W1; inv_s = 0.5f;  }
    else                 { f = f2 + (size_t)cl * P2; Hc = H2; Wc = W2; inv_s = 0.25f; }
    float acc = 0.0f;
#pragma unroll
    for (int ry = 0; ry < 2; ++ry) {
        float Y = by1 + ((float)oh + 0.25f + 0.5f * ry) * bh;
        bool vy = (Y >= -1.0f) && (Y <= (float)H0);
        float Yc = fminf(fmaxf(Y, 0.0f), (float)(H0 - 1));
        int y0 = (int)Yc;
        float ly = Yc - (float)y0;
#pragma unroll
        for (int rx = 0; rx < 2; ++rx) {
            float X = bx1 + ((float)ow + 0.25f + 0.5f * rx) * bw;
            bool vx = (X >= -1.0f) && (X <= (float)W0);
            float Xc = fminf(fmaxf(X, 0.0f), (float)(W0 - 1));
            int x0 = (int)Xc;
            float lx = Xc - (float)x0;
            float v;
            if (level == 0) {
                int y1i = min(y0 + 1, H0 - 1), x1i = min(x0 + 1, W0 - 1);
                float hy = 1.0f - ly, hx = 1.0f - lx;
                float v00 = f[y0 * W0 + x0],  v01 = f[y0 * W0 + x1i];
                float v10 = f[y1i * W0 + x0], v11 = f[y1i * W0 + x1i];
                v = hy * (hx * v00 + lx * v01) + ly * (hx * v10 + lx * v11);
            } else {
                int yb, xb; float wy[3], wxl[3];
                axis_w3_fb(y0, H0, Hc, inv_s, ly, yb, wy);
                axis_w3_fb(x0, W0, Wc, inv_s, lx, xb, wxl);
                v = 0.0f;
#pragma unroll
                for (int a = 0; a < 3; ++a) {
                    int row = min(yb + a, Hc - 1) * Wc;
                    float s = 0.0f;
#pragma unroll
                    for (int b = 0; b < 3; ++b)
                        s += wxl[b] * f[row + min(xb + b, Wc - 1)];
                    v += wy[a] * s;
                }
            }
            if (vy && vx) acc += v;
        }
    }
    out[i] = acc * 0.25f;
}

// ---------------- launch ----------------------------------------------------
extern "C" void kernel_launch(void* const* d_in, const int* in_sizes, int n_in,
                              void* d_out, int out_size, void* d_ws, size_t ws_size,
                              hipStream_t stream) {
    const float* f0    = (const float*)d_in[0];
    const float* f1    = (const float*)d_in[1];
    const float* f2    = (const float*)d_in[2];
    const float* boxes = (const float*)d_in[3];
    const int* img_h_p = (const int*)d_in[4];
    const int* img_w_p = (const int*)d_in[5];
    float* out = (float*)d_out;
    int N = in_sizes[3] / 4;

    if (ws_size >= WS_BYTES) {
        unsigned short* ws = (unsigned short*)d_ws;
        unsigned short* T0 = ws + T0_OFF;
        unsigned short* T1 = ws + T1_OFF;
        unsigned short* T2 = ws + T2_OFF;
        int n0 = ((P0 + 63) / 64) * 4;   // 3800
        int n1 = ((P1 + 63) / 64) * 4;   // 952
        int n2 = ((P2 + 63) / 64) * 4;   // 240
        transpose_all_kernel<<<n0 + n1 + n2, 256, 0, stream>>>(
            f0, f1, f2, T0, T1, T2, n0, n0 + n1);
        roi_align_sep_kernel<<<dim3(N, 6), 256, 0, stream>>>(
            T0, T1, T2, boxes, img_h_p, img_w_p, out);
    } else {
        int total = N * CTOT * OH * OW;
        roi_align_fused_fb_kernel<<<(total + 255) / 256, 256, 0, stream>>>(
            f0, f1, f2, boxes, img_h_p, img_w_p, out, total);
    }
}

// Round 11
// 156.568 us; speedup vs baseline: 1.0562x; 1.0562x over previous
//
#include <hip/hip_runtime.h>
#include <hip/hip_fp16.h>

#define H0 200
#define W0 304
#define H1 100
#define W1 152
#define H2 50
#define W2 76
#define CPL 256   // channels per level
#define CTOT 768
#define OH 7
#define OW 7
#define NPOS 49
#define CBLK 128   // channels per stage-2 block
#define SROWP 131  // sout row stride (floats)

#define P0 (H0*W0)   // 60800
#define P1 (H1*W1)   // 15200
#define P2 (H2*W2)   // 3800
#define T0_OFF ((size_t)0)
#define T1_OFF ((size_t)P0*CPL)
#define T2_OFF ((size_t)P0*CPL + (size_t)P1*CPL)
#define WS_ELEMS ((size_t)P0*CPL + (size_t)P1*CPL + (size_t)P2*CPL)
#define WS_BYTES (WS_ELEMS * 2)   // fp16 workspace: 40,857,600 B

__device__ __forceinline__ float hat01(float d) {
    return fmaxf(0.0f, 1.0f - fabsf(d));
}

__device__ __forceinline__ unsigned short f2h_rne(float x) {
    return __half_as_ushort(__float2half_rn(x));
}

// ------------- Stage 1: fused [C][P] fp32 -> [P][C] fp16 transpose ----------
__global__ void __launch_bounds__(256)
transpose_all_kernel(const float* __restrict__ f0, const float* __restrict__ f1,
                     const float* __restrict__ f2,
                     unsigned short* __restrict__ T0,
                     unsigned short* __restrict__ T1,
                     unsigned short* __restrict__ T2, int n0, int n01) {
    __shared__ unsigned short tile[64][72];   // [p_local][c_local]
    int b = blockIdx.x;
    const float* in; unsigned short* outp; int P; int rel;
    if (b < n0)       { in = f0; outp = T0; P = P0; rel = b; }
    else if (b < n01) { in = f1; outp = T1; P = P1; rel = b - n0; }
    else              { in = f2; outp = T2; P = P2; rel = b - n01; }
    int p0 = (rel >> 2) * 64;
    int c0 = (rel & 3) * 64;

    int q = threadIdx.x & 15;     // p-quad
    int r = threadIdx.x >> 4;     // 0..15 (c)
    bool full = (p0 + 64 <= P);
#pragma unroll
    for (int i = 0; i < 4; ++i) {
        int c = c0 + r + 16 * i;
        int p = p0 + 4 * q;
        float4 v;
        if (full) {
            v = *(const float4*)(in + (size_t)c * P + p);
        } else {
            v.x = (p + 0 < P) ? in[(size_t)c * P + p + 0] : 0.0f;
            v.y = (p + 1 < P) ? in[(size_t)c * P + p + 1] : 0.0f;
            v.z = (p + 2 < P) ? in[(size_t)c * P + p + 2] : 0.0f;
            v.w = (p + 3 < P) ? in[(size_t)c * P + p + 3] : 0.0f;
        }
        tile[4 * q + 0][r + 16 * i] = f2h_rne(v.x);
        tile[4 * q + 1][r + 16 * i] = f2h_rne(v.y);
        tile[4 * q + 2][r + 16 * i] = f2h_rne(v.z);
        tile[4 * q + 3][r + 16 * i] = f2h_rne(v.w);
    }
    __syncthreads();
    int q8 = threadIdx.x & 7;     // c-octet
    int r8 = threadIdx.x >> 3;    // 0..31 (p)
#pragma unroll
    for (int i = 0; i < 2; ++i) {
        int p = p0 + r8 + 32 * i;
        if (p < P) {
            uint4 w = *(const uint4*)&tile[r8 + 32 * i][8 * q8];
            *(uint4*)(outp + (size_t)p * CPL + c0 + 8 * q8) = w;
        }
    }
}

// ------------- Stage 2 -------------------------------------------------------
// R11: register-separable RoIAlign, PLAIN-C loads (no inline asm).
// R8-R10 NaN root cause (by elimination, consistent with all evidence):
// the asm double-buffer was live across a runtime while-loop BACK EDGE ->
// PHI nodes -> regalloc inserts v_mov copies at block boundaries -> a copy
// reads an in-flight asm-load destination before the load lands (compiler
// can't see the asm is a load; no waitcnt guards the copy) -> garbage.
// R6's asm worked ONLY because it was fully-unrolled straight-line code.
// Lesson: asm load destinations must never cross a basic-block boundary.
// Fix: ordinary C loads, TWO strips per iteration in one basic block ->
// compiler batches 2*TT loads with its own (correct) counted waitcnts.
// Algorithm unchanged: per ow-column iterate y-strips; per strip load TT
// x-taps once, x-combine to fp32, scatter into acc[7][4] with block-uniform
// y-weights (7 oh share each strip's loads -> ~2.8x fewer gathers on L1/L2).
// Clamped y-taps weight-folded onto the boundary strip (strip<->weight
// mapping unique). L0 keeps the direct path.

// direct path for L0 (4x4 taps), 16-lane groups, 3-4 consecutive positions
__device__ __forceinline__ void tap_loop_l0(const unsigned short* __restrict__ T,
                                            const int (*__restrict__ s_idx)[6],
                                            const float (*__restrict__ s_w)[6],
                                            float (*__restrict__ sout)[SROWP],
                                            int pstart, int pcount, int col,
                                            unsigned laneByte) {
    const char* Tb = (const char*)T;
    const __half2 hz = __float2half2_rn(0.0f);
    for (int pi = 0; pi < pcount; ++pi) {
        const int pos = pstart + pi;
        const int oh = pos / 7;
        const int ow = pos - oh * 7;
        unsigned yb[4]; float yw[4];
#pragma unroll
        for (int j2 = 0; j2 < 4; ++j2) {
            yb[j2] = (unsigned)s_idx[oh][j2] + laneByte;
            yw[j2] = s_w[oh][j2];
        }
        unsigned xb[4]; __half2 xw2[4];
#pragma unroll
        for (int j2 = 0; j2 < 4; ++j2) {
            xb[j2] = (unsigned)s_idx[7 + ow][j2];
            xw2[j2] = __float2half2_rn(s_w[7 + ow][j2]);
        }
        float a0 = 0.f, a1 = 0.f, a2 = 0.f, a3 = 0.f;
        float a4 = 0.f, a5 = 0.f, a6 = 0.f, a7 = 0.f;
#pragma unroll
        for (int r = 0; r < 4; ++r) {
            __half2 q0 = hz, q1 = hz, q2 = hz, q3 = hz;
#pragma unroll
            for (int b = 0; b < 4; ++b) {
                const uint4 v = *(const uint4*)(Tb + (yb[r] + xb[b]));
                const __half2 xw = xw2[b];
                q0 = __hfma2(xw, *(const __half2*)&v.x, q0);
                q1 = __hfma2(xw, *(const __half2*)&v.y, q1);
                q2 = __hfma2(xw, *(const __half2*)&v.z, q2);
                q3 = __hfma2(xw, *(const __half2*)&v.w, q3);
            }
            const float wa = yw[r];
            a0 = fmaf(wa, __low2float(q0), a0);  a1 = fmaf(wa, __high2float(q0), a1);
            a2 = fmaf(wa, __low2float(q1), a2);  a3 = fmaf(wa, __high2float(q1), a3);
            a4 = fmaf(wa, __low2float(q2), a4);  a5 = fmaf(wa, __high2float(q2), a5);
            a6 = fmaf(wa, __low2float(q3), a6);  a7 = fmaf(wa, __high2float(q3), a7);
        }
        float4 o0, o1;
        o0.x = a0 * 0.25f; o0.y = a1 * 0.25f; o0.z = a2 * 0.25f; o0.w = a3 * 0.25f;
        o1.x = a4 * 0.25f; o1.y = a5 * 0.25f; o1.z = a6 * 0.25f; o1.w = a7 * 0.25f;
        *(float4*)(&sout[pos][col])     = o0;
        *(float4*)(&sout[pos][col + 4]) = o1;
    }
}

// register-separable path for L1/L2. 8 groups of 32 lanes; groups 0..6 own
// ow columns (lane = 4 channels, 8B/tap). Two strips per iteration, plain C.
template<int TT, int YSTRIDE>
__device__ __forceinline__ void sep_cols(const unsigned short* __restrict__ T,
                                         const int (*__restrict__ s_idx)[6],
                                         const float (*__restrict__ s_w)[6],
                                         const int* __restrict__ s_yb,
                                         float (*__restrict__ sout)[SROWP],
                                         int tid, unsigned chalfByte, int Hc) {
    const int g = tid >> 5;            // 0..7 (group = ow column)
    const int l = tid & 31;            // lane: 4 channels (8B)
    if (g >= 7) return;                // spare group idles (no barriers inside)
    const int ow = g;
    unsigned xb[TT]; float xw[TT];
#pragma unroll
    for (int t = 0; t < TT; ++t) {
        xb[t] = (unsigned)s_idx[7 + ow][t] + chalfByte + (unsigned)(l * 8);
        xw[t] = s_w[7 + ow][t];
    }
    int b0[7];
#pragma unroll
    for (int o = 0; o < 7; ++o) b0[o] = s_yb[o];
    int ylo = b0[0], ybmax = b0[0];
#pragma unroll
    for (int o = 1; o < 7; ++o) { ylo = min(ylo, b0[o]); ybmax = max(ybmax, b0[o]); }
    const int yhi = min(ybmax + TT - 1, Hc - 1);

    float acc[7][4];
#pragma unroll
    for (int o = 0; o < 7; ++o) {
        acc[o][0] = 0.f; acc[o][1] = 0.f; acc[o][2] = 0.f; acc[o][3] = 0.f;
    }

    const char* Tb = (const char*)T;

#define SEP_CONSUME(V, SS)                                                     \
    {                                                                          \
        float xr0 = 0.f, xr1 = 0.f, xr2 = 0.f, xr3 = 0.f;                      \
        _Pragma("unroll")                                                      \
        for (int t = 0; t < TT; ++t) {                                         \
            const uint2 vv = V[t];                                             \
            float2 lo = __half22float2(*(const __half2*)&vv.x);                \
            float2 hi = __half22float2(*(const __half2*)&vv.y);                \
            xr0 = fmaf(xw[t], lo.x, xr0); xr1 = fmaf(xw[t], lo.y, xr1);        \
            xr2 = fmaf(xw[t], hi.x, xr2); xr3 = fmaf(xw[t], hi.y, xr3);        \
        }                                                                      \
        _Pragma("unroll")                                                      \
        for (int o = 0; o < 7; ++o) {                                          \
            int tt = (SS) - b0[o];                                             \
            if ((unsigned)tt < (unsigned)TT) {                                 \
                float wy = s_w[o][tt];                                         \
                acc[o][0] = fmaf(wy, xr0, acc[o][0]);                          \
                acc[o][1] = fmaf(wy, xr1, acc[o][1]);                          \
                acc[o][2] = fmaf(wy, xr2, acc[o][2]);                          \
                acc[o][3] = fmaf(wy, xr3, acc[o][3]);                          \
            }                                                                  \
        }                                                                      \
    }

    int s = ylo;
    for (; s + 1 <= yhi; s += 2) {
        const unsigned sB0 = (unsigned)s * (unsigned)YSTRIDE;
        uint2 va[TT], vb[TT];
        // both strips' loads issued in ONE basic block before any consume:
        // compiler batches 2*TT independent loads with correct counted waits
#pragma unroll
        for (int t = 0; t < TT; ++t)
            va[t] = *(const uint2*)(Tb + (sB0 + xb[t]));
#pragma unroll
        for (int t = 0; t < TT; ++t)
            vb[t] = *(const uint2*)(Tb + (sB0 + (unsigned)YSTRIDE + xb[t]));
        SEP_CONSUME(va, s);
        SEP_CONSUME(vb, s + 1);
    }
    if (s <= yhi) {
        const unsigned sB0 = (unsigned)s * (unsigned)YSTRIDE;
        uint2 va[TT];
#pragma unroll
        for (int t = 0; t < TT; ++t)
            va[t] = *(const uint2*)(Tb + (sB0 + xb[t]));
        SEP_CONSUME(va, s);
    }
#undef SEP_CONSUME

    const int ch = l * 4;
#pragma unroll
    for (int o = 0; o < 7; ++o) {
        *(float4*)(&sout[o * 7 + ow][ch]) =
            make_float4(acc[o][0] * 0.25f, acc[o][1] * 0.25f,
                        acc[o][2] * 0.25f, acc[o][3] * 0.25f);
    }
}

__global__ void __launch_bounds__(256, 4)
roi_align_sepcol_kernel(const unsigned short* __restrict__ T0p,
                        const unsigned short* __restrict__ T1p,
                        const unsigned short* __restrict__ T2p,
                        const float* __restrict__ boxes,
                        const int* __restrict__ img_h_p,
                        const int* __restrict__ img_w_p,
                        float* __restrict__ out) {
    __shared__ float sout[NPOS][SROWP];    // [pos][c_local]
    __shared__ int   s_idx[14][6];         // BYTE offsets: [0..6]=y(oh), [7..13]=x(ow)
    __shared__ float s_w[14][6];
    __shared__ int   s_yb[7];              // y strip base per oh (sep levels)

    const int n = blockIdx.x;
    const int j = blockIdx.y;              // 0,1=L1 (first/heaviest); 2,3=L0; 4,5=L2
    const int lev = (j < 2) ? 1 : ((j < 4) ? 0 : 2);
    const int chalf = j & 1;
    const int tid = threadIdx.x;

    const unsigned short* T; int Hc, Wc; float inv_s;
    if (lev == 0)      { T = T0p; Hc = H0; Wc = W0; inv_s = 1.0f;  }
    else if (lev == 1) { T = T1p; Hc = H1; Wc = W1; inv_s = 0.5f;  }
    else               { T = T2p; Hc = H2; Wc = W2; inv_s = 0.25f; }

    if (tid < 14) {
        int axis = (tid >= 7) ? 1 : 0;     // 0 = y, 1 = x
        int o = tid - axis * 7;
        float sx = (float)W0 / (float)img_w_p[0];
        float sy = (float)H0 / (float)img_h_p[0];
        float a1v, bs; int Hf, Hca, mul;
        if (axis) {
            a1v = boxes[n * 4 + 0] * sx;
            float a2v = boxes[n * 4 + 2] * sx;
            bs = fmaxf(a2v - a1v, 1.0f) * (1.0f / (float)OW);
            Hf = W0; Hca = Wc; mul = 1;
        } else {
            a1v = boxes[n * 4 + 1] * sy;
            float a2v = boxes[n * 4 + 3] * sy;
            bs = fmaxf(a2v - a1v, 1.0f) * (1.0f / (float)OH);
            Hf = H0; Hca = Hc; mul = Wc;
        }
        int idx[6]; float w[6];
#pragma unroll
        for (int t = 0; t < 6; ++t) { idx[t] = 0; w[t] = 0.0f; }
        if (lev == 0) {
#pragma unroll
            for (int r2 = 0; r2 < 2; ++r2) {
                float Y = a1v + ((float)o + 0.25f + 0.5f * (float)r2) * bs;
                float v = (Y >= -1.0f && Y <= (float)Hf) ? 1.0f : 0.0f;
                float Yc = fminf(fmaxf(Y, 0.0f), (float)(Hf - 1));
                int y0 = (int)Yc; float lf = Yc - (float)y0;
                idx[2 * r2]     = y0;                  w[2 * r2]     = (1.0f - lf) * v;
                idx[2 * r2 + 1] = min(y0 + 1, Hf - 1); w[2 * r2 + 1] = lf * v;
            }
        } else {
            int bases[2]; float w3[2][3];
#pragma unroll
            for (int r2 = 0; r2 < 2; ++r2) {
                float Y = a1v + ((float)o + 0.25f + 0.5f * (float)r2) * bs;
                float v = (Y >= -1.0f && Y <= (float)Hf) ? 1.0f : 0.0f;
                float Yc = fminf(fmaxf(Y, 0.0f), (float)(Hf - 1));
                int y0 = (int)Yc; float lf = Yc - (float)y0; float hf = 1.0f - lf;
                int yf1 = min(y0 + 1, Hf - 1);
                float yc0 = fminf(fmaxf(((float)y0 + 0.5f) * inv_s - 0.5f, 0.0f), (float)(Hca - 1));
                float yc1 = fminf(fmaxf(((float)yf1 + 0.5f) * inv_s - 0.5f, 0.0f), (float)(Hca - 1));
                int b2 = (int)yc0;
                bases[r2] = b2;
#pragma unroll
                for (int t2 = 0; t2 < 3; ++t2) {
                    float j2 = (float)(b2 + t2);
                    w3[r2][t2] = v * (hf * hat01(yc0 - j2) + lf * hat01(yc1 - j2));
                }
            }
            int dmax = (lev == 1) ? 3 : 2;   // geometry: box<=272px -> gap<=2.43/1.21
            int d = min(max(bases[1] - bases[0], 0), dmax);
            w[0] += w3[0][0]; w[1] += w3[0][1]; w[2] += w3[0][2];
            w[d] += w3[1][0]; w[d + 1] += w3[1][1]; w[d + 2] += w3[1][2];
#pragma unroll
            for (int t = 0; t < 6; ++t) idx[t] = min(bases[0] + t, Hca - 1);
            if (axis == 0) {
                // fold clamped-duplicate weights onto the boundary strip so
                // strip s <-> tap t = s - base is unique (static-index sweep)
#pragma unroll
                for (int t = 4; t >= 0; --t) {
                    if (bases[0] + t + 1 > Hca - 1) { w[t] += w[t + 1]; w[t + 1] = 0.0f; }
                }
                s_yb[o] = bases[0];
            }
        }
        // pre-scale to BYTE offset in T (row stride Wc*CPL elems, 2B/elem)
#pragma unroll
        for (int t = 0; t < 6; ++t) { s_idx[tid][t] = idx[t] * mul * CPL * 2; s_w[tid][t] = w[t]; }
    }
    __syncthreads();

    const unsigned chalfByte = (unsigned)(chalf * CBLK) * 2u;

    if (lev == 0) {
        const int grp = tid >> 4;              // 0..15: position group
        const int l16 = tid & 15;              // 0..15: 8 channels each
        const int col = l16 * 8;
        const unsigned laneByte = chalfByte + (unsigned)col * 2u;
        const int pstart = 3 * grp;
        const int pcount = (grp == 15) ? 4 : 3;
        tap_loop_l0(T, s_idx, s_w, sout, pstart, pcount, col, laneByte);
    } else if (lev == 1) {
        sep_cols<6, W1 * CPL * 2>(T, s_idx, s_w, s_yb, sout, tid, chalfByte, H1);
    } else {
        sep_cols<5, W2 * CPL * 2>(T, s_idx, s_w, s_yb, sout, tid, chalfByte, H2);
    }
    __syncthreads();

    // Writeback: out[n][lev*256 + chalf*128 + c][p], contiguous 128*49 floats.
    size_t obase = (size_t)n * CTOT * NPOS + (size_t)(lev * CPL + chalf * CBLK) * NPOS;
    int c = tid / NPOS;
    int p = tid - c * NPOS;
    for (int i = tid; i < CBLK * NPOS; i += 256) {
        out[obase + i] = sout[p][c];
        c += 5; p += 11;                   // 256 = 5*49 + 11
        if (p >= NPOS) { p -= NPOS; ++c; }
    }
}

// ---------------- Fallback (R1 kernel) if ws too small ----------------------
__device__ __forceinline__ void axis_w3_fb(int yf0, int Hf, int Hc, float inv_s,
                                           float lf, int& base, float* w) {
    int yf1 = min(yf0 + 1, Hf - 1);
    float hf = 1.0f - lf;
    float yc0 = fminf(fmaxf(((float)yf0 + 0.5f) * inv_s - 0.5f, 0.0f), (float)(Hc - 1));
    float yc1 = fminf(fmaxf(((float)yf1 + 0.5f) * inv_s - 0.5f, 0.0f), (float)(Hc - 1));
    base = (int)yc0;
#pragma unroll
    for (int r = 0; r < 3; ++r) {
        float j = (float)(base + r);
        w[r] = hf * hat01(yc0 - j) + lf * hat01(yc1 - j);
    }
}

__global__ void __launch_bounds__(256)
roi_align_fused_fb_kernel(const float* __restrict__ f0,
                          const float* __restrict__ f1,
                          const float* __restrict__ f2,
                          const float* __restrict__ boxes,
                          const int* __restrict__ img_h_p,
                          const int* __restrict__ img_w_p,
                          float* __restrict__ out,
                          int total) {
    int i = blockIdx.x * blockDim.x + threadIdx.x;
    if (i >= total) return;
    int ow = i % OW;
    int t = i / OW;
    int oh = t % OH; t /= OH;
    int c = t % CTOT;
    int n = t / CTOT;
    float sx = (float)W0 / (float)img_w_p[0];
    float sy = (float)H0 / (float)img_h_p[0];
    float bx1 = boxes[n * 4 + 0] * sx;
    float by1 = boxes[n * 4 + 1] * sy;
    float bw = fmaxf(boxes[n * 4 + 2] * sx - bx1, 1.0f) / OW;
    float bh = fmaxf(boxes[n * 4 + 3] * sy - by1, 1.0f) / OH;
    int level = c >> 8;
    int cl = c & (CPL - 1);
    const float* f;
    int Hc, Wc; float inv_s;
    if (level == 0)      { f = f0 + (size_t)cl * P0; Hc = H0; Wc = W0; inv_s = 1.0f;  }
    else if (level == 1) { f = f1 + (size_t)cl * P1; Hc = H1; Wc = W1; inv_s = 0.5f;  }
    else                 { f = f2 + (size_t)cl * P2; Hc = H2; Wc = W2; inv_s = 0.25f; }
    float acc = 0.0f;
#pragma unroll
    for (int ry = 0; ry < 2; ++ry) {
        float Y = by1 + ((float)oh + 0.25f + 0.5f * ry) * bh;
        bool vy = (Y >= -1.0f) && (Y <= (float)H0);
        float Yc = fminf(fmaxf(Y, 0.0f), (float)(H0 - 1));
        int y0 = (int)Yc;
        float ly = Yc - (float)y0;
#pragma unroll
        for (int rx = 0; rx < 2; ++rx) {
            float X = bx1 + ((float)ow + 0.25f + 0.5f * rx) * bw;
            bool vx = (X >= -1.0f) && (X <= (float)W0);
            float Xc = fminf(fmaxf(X, 0.0f), (float)(W0 - 1));
            int x0 = (int)Xc;
            float lx = Xc - (float)x0;
            float v;
            if (level == 0) {
                int y1i = min(y0 + 1, H0 - 1), x1i = min(x0 + 1, W0 - 1);
                float hy = 1.0f - ly, hx = 1.0f - lx;
                float v00 = f[y0 * W0 + x0],  v01 = f[y0 * W0 + x1i];
                float v10 = f[y1i * W0 + x0], v11 = f[y1i * W0 + x1i];
                v = hy * (hx * v00 + lx * v01) + ly * (hx * v10 + lx * v11);
            } else {
                int yb, xb; float wy[3], wxl[3];
                axis_w3_fb(y0, H0, Hc, inv_s, ly, yb, wy);
                axis_w3_fb(x0, W0, Wc, inv_s, lx, xb, wxl);
                v = 0.0f;
#pragma unroll
                for (int a = 0; a < 3; ++a) {
                    int row = min(yb + a, Hc - 1) * Wc;
                    float s = 0.0f;
#pragma unroll
                    for (int b = 0; b < 3; ++b)
                        s += wxl[b] * f[row + min(xb + b, Wc - 1)];
                    v += wy[a] * s;
                }
            }
            if (vy && vx) acc += v;
        }
    }
    out[i] = acc * 0.25f;
}

// ---------------- launch ----------------------------------------------------
extern "C" void kernel_launch(void* const* d_in, const int* in_sizes, int n_in,
                              void* d_out, int out_size, void* d_ws, size_t ws_size,
                              hipStream_t stream) {
    const float* f0    = (const float*)d_in[0];
    const float* f1    = (const float*)d_in[1];
    const float* f2    = (const float*)d_in[2];
    const float* boxes = (const float*)d_in[3];
    const int* img_h_p = (const int*)d_in[4];
    const int* img_w_p = (const int*)d_in[5];
    float* out = (float*)d_out;
    int N = in_sizes[3] / 4;

    if (ws_size >= WS_BYTES) {
        unsigned short* ws = (unsigned short*)d_ws;
        unsigned short* T0 = ws + T0_OFF;
        unsigned short* T1 = ws + T1_OFF;
        unsigned short* T2 = ws + T2_OFF;
        int n0 = ((P0 + 63) / 64) * 4;   // 3800
        int n1 = ((P1 + 63) / 64) * 4;   // 952
        int n2 = ((P2 + 63) / 64) * 4;   // 240
        transpose_all_kernel<<<n0 + n1 + n2, 256, 0, stream>>>(
            f0, f1, f2, T0, T1, T2, n0, n0 + n1);
        roi_align_sepcol_kernel<<<dim3(N, 6), 256, 0, stream>>>(
            T0, T1, T2, boxes, img_h_p, img_w_p, out);
    } else {
        int total = N * CTOT * OH * OW;
        roi_align_fused_fb_kernel<<<(total + 255) / 256, 256, 0, stream>>>(
            f0, f1, f2, boxes, img_h_p, img_w_p, out, total);
    }
}